// Round 1
// 871.717 us; speedup vs baseline: 1.3039x; 1.3039x over previous
//
#include <hip/hip_runtime.h>

#define N_NODES 100000
#define N_EDGES 3200000
#define IN_F    128
#define EDGE_F  16
#define OUT_F   128
#define K_TOT   144   // IN_F + EDGE_F

// ---- workspace layout (bytes) ----
// counts  : int[100000]            @ 0
// offsets : int[100001]            @ 400000
// partials: int[256]               @ 800016
// csr2    : int2[3200000]          @ 801040    (25.6 MB: {edge id, row id})
// Se      : float[100000*16]       @ 26401040
// total ~32.8 MB
// rank    : int[3200000] lives in d_out (51.2 MB) — dead before gather_k
//           writes Sx there.

__global__ void count_k(const int* __restrict__ col, int* __restrict__ counts,
                        int* __restrict__ rank) {
    int e = blockIdx.x * blockDim.x + threadIdx.x;
    if (e < N_EDGES) rank[e] = atomicAdd(&counts[col[e]], 1);
}

// per-chunk (512) exclusive scan; chunk totals -> partials
__global__ void scan1_k(const int* __restrict__ counts, int* __restrict__ offsets,
                        int* __restrict__ partials) {
    __shared__ int s[512];
    int i = blockIdx.x * 512 + threadIdx.x;
    int v = (i < N_NODES) ? counts[i] : 0;
    s[threadIdx.x] = v;
    __syncthreads();
    for (int d = 1; d < 512; d <<= 1) {
        int t = (threadIdx.x >= d) ? s[threadIdx.x - d] : 0;
        __syncthreads();
        s[threadIdx.x] += t;
        __syncthreads();
    }
    if (i < N_NODES) offsets[i] = s[threadIdx.x] - v;   // exclusive within chunk
    if (threadIdx.x == 511) partials[blockIdx.x] = s[511];
}

// exclusive scan of the 196 chunk totals (single block)
__global__ void scan2_k(int* partials) {
    __shared__ int s[256];
    int v = (threadIdx.x < 196) ? partials[threadIdx.x] : 0;
    s[threadIdx.x] = v;
    __syncthreads();
    for (int d = 1; d < 256; d <<= 1) {
        int t = (threadIdx.x >= d) ? s[threadIdx.x - d] : 0;
        __syncthreads();
        s[threadIdx.x] += t;
        __syncthreads();
    }
    if (threadIdx.x < 196) partials[threadIdx.x] = s[threadIdx.x] - v;
}

__global__ void scan3_k(int* __restrict__ offsets, const int* __restrict__ partials) {
    int i = blockIdx.x * 512 + threadIdx.x;
    if (i < N_NODES) offsets[i] += partials[blockIdx.x];
    if (i == 0) offsets[N_NODES] = N_EDGES;
}

// No atomics: position = offsets[col] + rank (rank captured in count_k).
// Also pre-gathers row[e] (coalesced here!) so gather_k never touches `row`.
__global__ void fill_k(const int* __restrict__ col, const int* __restrict__ row,
                       const int* __restrict__ rank, const int* __restrict__ offsets,
                       int2* __restrict__ csr2) {
    int e = blockIdx.x * blockDim.x + threadIdx.x;
    if (e < N_EDGES) {
        int c = col[e];
        int pos = offsets[c] + rank[e];
        csr2[pos] = make_int2(e, row[e]);
    }
}

// One wave per node. csr2 gives {e, row} in one coalesced 8B load (no dependent
// row gather). x rows read as float4 (16B/lane), TWO rows per wave-instruction
// (lane halves), 8 pair-loads deep -> 16 rows / 128B-per-lane in flight.
// ea rows read as float4 across all 64 lanes -> 16 edges per instruction.
__global__ __launch_bounds__(256) void gather_k(
        const float* __restrict__ x, const float* __restrict__ ea,
        const int* __restrict__ offsets, const int2* __restrict__ csr2,
        float* __restrict__ Sx, float* __restrict__ Se) {
    const int wave = threadIdx.x >> 6;
    const int lane = threadIdx.x & 63;
    const int n = blockIdx.x * 4 + wave;   // 25000 blocks * 4 waves = 100000

    const int off0 = offsets[n];
    const int deg  = offsets[n + 1] - off0;

    const int half = lane >> 5;   // x: which row of the pair
    const int l31  = lane & 31;   // x: float4 slot within row
    const int qgrp = lane >> 4 == 0 ? lane >> 2 : lane >> 2; // (kept simple below)
    const int eg16 = lane >> 2;   // ea: edge within 16-group
    const int l3   = lane & 3;    // ea: float4 slot within row

    float4 ax = make_float4(0.f, 0.f, 0.f, 0.f);
    float4 se = make_float4(0.f, 0.f, 0.f, 0.f);
    (void)qgrp;

    for (int base = 0; base < deg; base += 64) {
        int m = deg - base; if (m > 64) m = 64;
        int e = 0, r = 0;
        if (lane < m) {
            int2 er = csr2[off0 + base + lane];   // coalesced: 64 pairs in 1 load
            e = er.x; r = er.y;
        }
        int j = 0;
        for (; j + 16 <= m; j += 16) {
            int r0 = __shfl(r, j + 0  + half);
            int r1 = __shfl(r, j + 2  + half);
            int r2 = __shfl(r, j + 4  + half);
            int r3 = __shfl(r, j + 6  + half);
            int r4 = __shfl(r, j + 8  + half);
            int r5 = __shfl(r, j + 10 + half);
            int r6 = __shfl(r, j + 12 + half);
            int r7 = __shfl(r, j + 14 + half);
            int ej = __shfl(e, j + eg16);
            float4 v0 = ((const float4*)(x + (size_t)r0 * IN_F))[l31];
            float4 v1 = ((const float4*)(x + (size_t)r1 * IN_F))[l31];
            float4 v2 = ((const float4*)(x + (size_t)r2 * IN_F))[l31];
            float4 v3 = ((const float4*)(x + (size_t)r3 * IN_F))[l31];
            float4 v4 = ((const float4*)(x + (size_t)r4 * IN_F))[l31];
            float4 v5 = ((const float4*)(x + (size_t)r5 * IN_F))[l31];
            float4 v6 = ((const float4*)(x + (size_t)r6 * IN_F))[l31];
            float4 v7 = ((const float4*)(x + (size_t)r7 * IN_F))[l31];
            float4 w  = ((const float4*)(ea + (size_t)ej * EDGE_F))[l3];
            ax.x += (v0.x + v1.x) + (v2.x + v3.x) + (v4.x + v5.x) + (v6.x + v7.x);
            ax.y += (v0.y + v1.y) + (v2.y + v3.y) + (v4.y + v5.y) + (v6.y + v7.y);
            ax.z += (v0.z + v1.z) + (v2.z + v3.z) + (v4.z + v5.z) + (v6.z + v7.z);
            ax.w += (v0.w + v1.w) + (v2.w + v3.w) + (v4.w + v5.w) + (v6.w + v7.w);
            se.x += w.x; se.y += w.y; se.z += w.z; se.w += w.w;
        }
        // tail: 2 x-rows per step (pair trick), 2 ea rows on lanes 0..7
        for (; j < m; j += 2) {
            int rj = __shfl(r, j + half);
            if (j + half < m) {
                float4 v = ((const float4*)(x + (size_t)rj * IN_F))[l31];
                ax.x += v.x; ax.y += v.y; ax.z += v.z; ax.w += v.w;
            }
            int eg = eg16 & 1;
            int ej = __shfl(e, j + eg);
            if (lane < 8 && (j + eg) < m) {
                float4 w = ((const float4*)(ea + (size_t)ej * EDGE_F))[l3];
                se.x += w.x; se.y += w.y; se.z += w.z; se.w += w.w;
            }
        }
    }

    // combine the two row-parity halves for x
    ax.x += __shfl_xor(ax.x, 32);
    ax.y += __shfl_xor(ax.y, 32);
    ax.z += __shfl_xor(ax.z, 32);
    ax.w += __shfl_xor(ax.w, 32);
    // reduce se across the 16 edge-groups (lanes with same lane&3)
    #pragma unroll
    for (int off = 4; off < 64; off <<= 1) {
        se.x += __shfl_xor(se.x, off);
        se.y += __shfl_xor(se.y, off);
        se.z += __shfl_xor(se.z, off);
        se.w += __shfl_xor(se.w, off);
    }
    if (lane < 32) ((float4*)(Sx + (size_t)n * IN_F))[l31] = ax;
    if (lane < 4)  ((float4*)(Se + (size_t)n * EDGE_F))[l3] = se;
}

// [100000 x 144] @ [144 x 128]^T GEMM with per-node deg*b bias and /deg.
// Block: 256 thr = (to 0..31: 4 outputs) x (tn 0..7: 4 nodes). Tile = 32 nodes.
// One tile per block (grid 3125). In-place on d_out: block stages its own S
// rows to LDS before overwriting them.
#define TILE_N 32
__global__ __launch_bounds__(256) void gemm_k(
        const float* __restrict__ Sx, const float* __restrict__ Se,
        const int* __restrict__ offsets, const float* __restrict__ W,
        const float* __restrict__ b, float* __restrict__ out) {
    __shared__ float Wt[72 * 132];   // half of W, transposed [k][o], padded row 132
    __shared__ float Sl[144 * 36];   // S tile transposed [k][n], padded row 36

    int tid = threadIdx.x;
    int to4 = (tid & 31) * 4;
    int tn4 = (tid >> 5) * 4;
    int n0 = blockIdx.x * TILE_N;

    // stage Sx rows (coalesced read, transposed LDS write)
    for (int idx = tid; idx < TILE_N * IN_F; idx += 256) {
        int n = idx >> 7, k = idx & 127;
        Sl[k * 36 + n] = Sx[(size_t)(n0 + n) * IN_F + k];
    }
    // stage Se rows
    for (int idx = tid; idx < TILE_N * EDGE_F; idx += 256) {
        int n = idx >> 4, k = idx & 15;
        Sl[(IN_F + k) * 36 + n] = Se[(size_t)(n0 + n) * EDGE_F + k];
    }

    float4 a0 = make_float4(0,0,0,0), a1 = make_float4(0,0,0,0);
    float4 a2 = make_float4(0,0,0,0), a3 = make_float4(0,0,0,0);

    for (int half = 0; half < 2; ++half) {
        __syncthreads();   // S staged (half 0) / prev half compute done
        int kbase = half * 72;
        for (int idx = tid; idx < 72 * 128; idx += 256) {
            int o = idx / 72, kl = idx % 72;          // coalesced W read
            Wt[kl * 132 + o] = W[(size_t)o * K_TOT + kbase + kl];
        }
        __syncthreads();

        #pragma unroll 4
        for (int kl = 0; kl < 72; ++kl) {
            float4 w4 = *(const float4*)&Wt[kl * 132 + to4];
            float4 s4 = *(const float4*)&Sl[(kbase + kl) * 36 + tn4];
            a0.x += s4.x * w4.x; a0.y += s4.x * w4.y; a0.z += s4.x * w4.z; a0.w += s4.x * w4.w;
            a1.x += s4.y * w4.x; a1.y += s4.y * w4.y; a1.z += s4.y * w4.z; a1.w += s4.y * w4.w;
            a2.x += s4.z * w4.x; a2.y += s4.z * w4.y; a2.z += s4.z * w4.z; a2.w += s4.z * w4.w;
            a3.x += s4.w * w4.x; a3.y += s4.w * w4.y; a3.z += s4.w * w4.z; a3.w += s4.w * w4.w;
        }
    }

    float4 b4 = *(const float4*)&b[to4];
    float4 accs[4] = {a0, a1, a2, a3};
    #pragma unroll
    for (int j = 0; j < 4; ++j) {
        int n = n0 + tn4 + j;
        float fdeg = (float)(offsets[n + 1] - offsets[n]);
        float inv = 1.0f / fmaxf(fdeg, 1.0f);
        float4 o4;
        o4.x = (accs[j].x + fdeg * b4.x) * inv;
        o4.y = (accs[j].y + fdeg * b4.y) * inv;
        o4.z = (accs[j].z + fdeg * b4.z) * inv;
        o4.w = (accs[j].w + fdeg * b4.w) * inv;
        *(float4*)&out[(size_t)n * OUT_F + to4] = o4;
    }
}

extern "C" void kernel_launch(void* const* d_in, const int* in_sizes, int n_in,
                              void* d_out, int out_size, void* d_ws, size_t ws_size,
                              hipStream_t stream) {
    const float* x  = (const float*)d_in[0];
    const int*   ei = (const int*)d_in[1];     // int32 per harness convention
    const float* ea = (const float*)d_in[2];
    const float* W  = (const float*)d_in[3];
    const float* b  = (const float*)d_in[4];
    float* out = (float*)d_out;

    char* ws = (char*)d_ws;
    int*   counts   = (int*)(ws + 0);
    int*   offsets  = (int*)(ws + 400000);
    int*   partials = (int*)(ws + 800016);
    int2*  csr2     = (int2*)(ws + 801040);
    float* Se       = (float*)(ws + 26401040);
    int*   rank     = (int*)d_out;             // dead before gather_k writes Sx

    const int* row = ei;             // edge_index[0]
    const int* col = ei + N_EDGES;   // edge_index[1]

    hipMemsetAsync(counts, 0, N_NODES * sizeof(int), stream);
    count_k<<<(N_EDGES + 255) / 256, 256, 0, stream>>>(col, counts, rank);
    scan1_k<<<196, 512, 0, stream>>>(counts, offsets, partials);
    scan2_k<<<1, 256, 0, stream>>>(partials);
    scan3_k<<<196, 512, 0, stream>>>(offsets, partials);
    fill_k<<<(N_EDGES + 255) / 256, 256, 0, stream>>>(col, row, rank, offsets, csr2);
    gather_k<<<N_NODES / 4, 256, 0, stream>>>(x, ea, offsets, csr2, out, Se);
    gemm_k<<<3125, 256, 0, stream>>>(out, Se, offsets, W, b, out);
}